// Round 8
// baseline (297.600 us; speedup 1.0000x reference)
//
#include <hip/hip_runtime.h>
#include <hip/hip_bf16.h>

typedef __attribute__((ext_vector_type(8))) short bf16x8;
typedef __attribute__((ext_vector_type(4))) short shortx4;
typedef __attribute__((ext_vector_type(4))) float floatx4;
typedef __attribute__((ext_vector_type(16))) float floatx16;
typedef __attribute__((ext_vector_type(2))) unsigned uint2v;

// ---------- helpers ----------

__device__ __forceinline__ unsigned short f2b(float f) {
    union { float f; unsigned int u; } v; v.f = f;
    unsigned int r = (v.u + 0x7FFFu + ((v.u >> 16) & 1u)) >> 16;
    return (unsigned short)r;
}

__device__ __forceinline__ unsigned int cvtpk(float a, float b) {
    unsigned int r;
    asm("v_cvt_pk_bf16_f32 %0, %1, %2" : "=v"(r) : "v"(a), "v"(b));
    return r;
}

__device__ __forceinline__ void gload_lds16(const void* g, void* l) {
    __builtin_amdgcn_global_load_lds(
        (const __attribute__((address_space(1))) void*)g,
        (__attribute__((address_space(3))) void*)l, 16, 0, 0);
}

__device__ __forceinline__ float xswap32(float v) {
    uint2v r = __builtin_amdgcn_permlane32_swap(__float_as_uint(v), __float_as_uint(v), false, false);
    return __uint_as_float((threadIdx.x & 32) ? r[0] : r[1]);
}

// ---------- fp32 -> bf16 convert ----------

__global__ __launch_bounds__(256) void f2b_kernel(const float* __restrict__ in,
                                                  unsigned short* __restrict__ out,
                                                  int n) {
    int i = (blockIdx.x * 256 + threadIdx.x) * 4;
    if (i >= n) return;
    floatx4 v = *(const floatx4*)&in[i];
    shortx4 o;
    o[0] = (short)f2b(v[0]); o[1] = (short)f2b(v[1]);
    o[2] = (short)f2b(v[2]); o[3] = (short)f2b(v[3]);
    *(shortx4*)&out[i] = o;
}

// ---------- GEMM1: 256x256 8-phase counted-vmcnt (T2+T3+T4+T5) ----------
// C[8192,3072] = A[8192,1024] @ B[3072,1024]^T, epilogue routes Q/K/Vt.
// 8 waves (2M x 4N), wave tile 128x64, BK=64, dbuf LDS 128 KB.
// Per K-tile: 4 phases = (fihalf, kk) quadrants; each phase: 8 swizzled
// ds_read_b128 + 1 half-tile stage (2 gload_lds) + raw barriers + 16 MFMA.
// Stage schedule (region-retirement verified):
//   p1: A-fh1(T+1)->nb   p2: B-kk1(T+1)->nb   p3: A-fh0(T+2)->buf   p4: B-kk0(T+2)->buf
// vmcnt(6) @p1, vmcnt(8) @p4 (counted, never 0 in the loop).

#define VMC(N) asm volatile("s_waitcnt vmcnt(" #N ")" ::: "memory")
#define SCHED0 __builtin_amdgcn_sched_barrier(0)

#define GPHASE(BUF, FH, KK, STAGE_STMT, VM_STMT)                              \
  {                                                                           \
    bf16x8 av[4], bv[4];                                                      \
    _Pragma("unroll") for (int i = 0; i < 4; i++)                             \
      av[i] = *(const bf16x8*)&Al[BUF][FH][wm][i * 16 + low]                  \
                  [((KK) * 32 + hi * 8) ^ ((low & 7) << 3)];                  \
    _Pragma("unroll") for (int j = 0; j < 4; j++)                             \
      bv[j] = *(const bf16x8*)&Bl[BUF][KK][wn * 64 + j * 16 + low][bswz];     \
    STAGE_STMT;                                                               \
    VM_STMT;                                                                  \
    SCHED0;                                                                   \
    __builtin_amdgcn_s_barrier();                                             \
    SCHED0;                                                                   \
    __builtin_amdgcn_s_setprio(1);                                            \
    _Pragma("unroll") for (int i = 0; i < 4; i++)                             \
      _Pragma("unroll") for (int j = 0; j < 4; j++)                           \
        acc[(FH) * 4 + i][j] = __builtin_amdgcn_mfma_f32_16x16x32_bf16(       \
            av[i], bv[j], acc[(FH) * 4 + i][j], 0, 0, 0);                     \
    __builtin_amdgcn_s_setprio(0);                                            \
    SCHED0;                                                                   \
    __builtin_amdgcn_s_barrier();                                             \
    SCHED0;                                                                   \
  }

__global__ __launch_bounds__(512, 2) void gemm8p(
    const unsigned short* __restrict__ A, const unsigned short* __restrict__ B,
    unsigned short* __restrict__ Qo, unsigned short* __restrict__ Ko,
    unsigned short* __restrict__ Vt)
{
    // A: [buf][fihalf][wmhalf][64 rows][64 k] ; B: [buf][kk][256 rows][32 k]
    __shared__ unsigned short Al[2][2][2][64][64];   // 64 KB
    __shared__ unsigned short Bl[2][2][256][32];     // 64 KB

    const int t = threadIdx.x, lane = t & 63, w = t >> 6;
    const int low = lane & 15, hi = lane >> 4;
    const int wm = w >> 2, wn = w & 3;
    const int bswz = (hi ^ ((low >> 1) & 3)) * 8;

    const int swz = (blockIdx.x & 7) * 48 + (blockIdx.x >> 3);   // 384 blocks, 8 XCDs
    const int m0 = (swz / 12) << 8, n0 = (swz % 12) << 8;

    floatx4 acc[8][4];
#pragma unroll
    for (int i = 0; i < 8; i++)
#pragma unroll
        for (int j = 0; j < 4; j++) acc[i][j] = (floatx4)0.0f;

    // staging: one unit = 16 KB = 2 gload_lds/thread, lane-contiguous LDS dest,
    // pre-swizzled global source (rule #21).
    auto stageA = [&](int b, int f, int kt) {
        const int r6 = t >> 3, ch = t & 7;
        const int sc = (ch * 8) ^ ((r6 & 7) << 3);
#pragma unroll
        for (int l = 0; l < 2; l++) {
            const int gr = m0 + l * 128 + f * 64 + r6;
            gload_lds16(A + (size_t)gr * 1024 + kt * 64 + sc, &Al[b][f][l][r6][ch * 8]);
        }
    };
    auto stageB = [&](int b, int k, int kt) {
        const int r7 = t >> 2, ch = t & 3;
        const int c = ch ^ ((r7 >> 1) & 3);
#pragma unroll
        for (int l = 0; l < 2; l++) {
            const int gr = n0 + l * 128 + r7;
            gload_lds16(B + (size_t)gr * 1024 + kt * 64 + k * 32 + c * 8,
                        &Bl[b][k][l * 128 + r7][ch * 8]);
        }
    };

    // prologue: tile0 fully + tile1's first two units; confirm tile0-p1 inputs.
    stageA(0, 0, 0); stageB(0, 0, 0);
    stageA(0, 1, 0); stageB(0, 1, 0);
    stageA(1, 0, 1); stageB(1, 0, 1);
    VMC(8);
    SCHED0; __builtin_amdgcn_s_barrier(); SCHED0;

    for (int T = 0; T < 16; ++T) {
        const int buf = T & 1, nb = buf ^ 1;
        const int k1 = (T + 1) & 15, k2 = (T + 2) & 15;
        GPHASE(buf, 0, 0, stageA(nb, 1, k1), VMC(6));
        GPHASE(buf, 0, 1, stageB(nb, 1, k1), (void)0);
        GPHASE(buf, 1, 0, stageA(buf, 0, k2), (void)0);
        GPHASE(buf, 1, 1, stageB(buf, 0, k2), VMC(8));
    }

    // epilogue: route cols into Q [bh][n][64], K [bh][n][64], Vt [bh][64][n]
#pragma unroll
    for (int fi = 0; fi < 8; fi++) {
        const int mrow = m0 + wm * 128 + fi * 16 + (hi << 2);
#pragma unroll
        for (int fj = 0; fj < 4; fj++) {
            const int col = n0 + wn * 64 + fj * 16 + low;
            const int sel = col >> 10;
            const int h = (col >> 6) & 15;
            const int d = col & 63;
            const int bb = mrow >> 11;
            const int n = mrow & 2047;
            const int bh = bb * 16 + h;
            if (sel == 2) {
                shortx4 v;
#pragma unroll
                for (int r = 0; r < 4; r++) v[r] = (short)f2b(acc[fi][fj][r]);
                *(shortx4*)&Vt[(size_t)(bh * 64 + d) * 2048 + n] = v;
            } else {
                unsigned short* dst = (sel == 0 ? Qo : Ko) + (size_t)(bh * 2048 + n) * 64 + d;
#pragma unroll
                for (int r = 0; r < 4; r++) dst[(size_t)r * 64] = f2b(acc[fi][fj][r]);
            }
        }
    }
}

// ---------- GEMM2: m97-structure 128x128 (unchanged), fp32 C + bias ----------

__global__ __launch_bounds__(256) void gemm_bt(
    const unsigned short* __restrict__ A, const unsigned short* __restrict__ B,
    int M, int N, int K,
    float* __restrict__ Cout, const float* __restrict__ bias)
{
    __shared__ unsigned short As[128 * 64];
    __shared__ unsigned short Bs[128 * 64];

    const int t = threadIdx.x;
    const int lane = t & 63, wid = t >> 6;
    const int wr = wid >> 1, wc = wid & 1;
    const int nbn = N >> 7;

    const int nwg = gridDim.x;
    const int cpx = nwg >> 3;
    const int gid = blockIdx.x;
    const int swz = (gid & 7) * cpx + (gid >> 3);
    const int m0 = (swz / nbn) << 7;
    const int n0 = (swz % nbn) << 7;

    floatx4 acc[4][4];
#pragma unroll
    for (int i = 0; i < 4; i++)
#pragma unroll
        for (int j = 0; j < 4; j++) acc[i][j] = (floatx4)0.0f;

    const int row_s = t >> 3;
    const int ch = t & 7;

    const int nkt = K >> 6;
    for (int kt = 0; kt < nkt; ++kt) {
        const int k0 = kt << 6;
#pragma unroll
        for (int it = 0; it < 4; ++it) {
            const int row = row_s + it * 32;
            gload_lds16(A + (size_t)(m0 + row) * K + k0 + ch * 8, &As[row * 64 + ch * 8]);
            gload_lds16(B + (size_t)(n0 + row) * K + k0 + ch * 8, &Bs[row * 64 + ch * 8]);
        }
        __syncthreads();
#pragma unroll
        for (int ks = 0; ks < 2; ++ks) {
            bf16x8 a[4], b[4];
#pragma unroll
            for (int i = 0; i < 4; i++)
                a[i] = *(const bf16x8*)&As[(64 * wr + 16 * i + (lane & 15)) * 64 + ks * 32 + (lane >> 4) * 8];
#pragma unroll
            for (int j = 0; j < 4; j++)
                b[j] = *(const bf16x8*)&Bs[(64 * wc + 16 * j + (lane & 15)) * 64 + ks * 32 + (lane >> 4) * 8];
#pragma unroll
            for (int i = 0; i < 4; i++)
#pragma unroll
                for (int j = 0; j < 4; j++)
                    acc[i][j] = __builtin_amdgcn_mfma_f32_16x16x32_bf16(a[i], b[j], acc[i][j], 0, 0, 0);
        }
        __syncthreads();
    }

#pragma unroll
    for (int i = 0; i < 4; i++) {
        const int mrow = m0 + 64 * wr + 16 * i + ((lane >> 4) << 2);
#pragma unroll
        for (int j = 0; j < 4; j++) {
            const int col = n0 + 64 * wc + 16 * j + (lane & 15);
            const float bi = bias[col];
#pragma unroll
            for (int r = 0; r < 4; r++)
                Cout[(size_t)(mrow + r) * N + col] = acc[i][j][r] + bi;
        }
    }
}

// ---------- flash attention (unchanged from R6: max-free softmax) ----------

__global__ __launch_bounds__(256) void attn_kernel(
    const unsigned short* __restrict__ Q, const unsigned short* __restrict__ Kp,
    const unsigned short* __restrict__ Vt, unsigned short* __restrict__ O)
{
    __shared__ unsigned short KV[2][2][4096];   // [buf][K/V][64 x 64], 32 KB

    const int t = threadIdx.x, lane = t & 63;
    const int l31 = lane & 31, hb = lane >> 5;
    const int bid = blockIdx.x;
    const int x = bid & 7, seq = bid >> 3;
    const int head = x + 8 * (seq & 7);
    const int qb = seq >> 3;
    const size_t base_nd = (size_t)head * 2048 * 64;
    const int q0w = qb * 128 + (t >> 6) * 32;

    const int s_row = t >> 3, s_ch = t & 7;
    const int xk = (l31 & 7) << 3;
    int foff[2][4];
#pragma unroll
    for (int blk = 0; blk < 2; blk++)
#pragma unroll
        for (int dstep = 0; dstep < 4; dstep++)
            foff[blk][dstep] = (blk * 32 + l31) * 64 + ((dstep * 16 + hb * 8) ^ xk);

    const float sc = 0.18033688011112042f;  // (1/8) * log2(e)

    bf16x8 qf[4];
#pragma unroll
    for (int dstep = 0; dstep < 4; dstep++) {
        union { bf16x8 v; unsigned short s[8]; unsigned u[4]; } in, ov;
        in.v = *(const bf16x8*)&Q[base_nd + (size_t)(q0w + l31) * 64 + dstep * 16 + hb * 8];
#pragma unroll
        for (int p = 0; p < 4; p++) {
            const float f0 = __uint_as_float((unsigned)in.s[2 * p] << 16) * sc;
            const float f1 = __uint_as_float((unsigned)in.s[2 * p + 1] << 16) * sc;
            ov.u[p] = cvtpk(f0, f1);
        }
        qf[dstep] = ov.v;
    }

    floatx16 o2[2];
    o2[0] = (floatx16)0.0f; o2[1] = (floatx16)0.0f;
    floatx4 l4 = (floatx4)0.0f;

#pragma unroll
    for (int rnd = 0; rnd < 2; rnd++) {
        const int row = s_row + rnd * 32;
        const int swr = (s_ch * 8) ^ ((row & 7) << 3);
        const int c = rnd * 256 + t;
        gload_lds16(Kp + base_nd + (size_t)row * 64 + swr, &KV[0][0][c * 8]);
        gload_lds16(Vt + base_nd + (size_t)row * 2048 + swr, &KV[0][1][c * 8]);
    }
    __syncthreads();

    for (int nt = 0; nt < 32; ++nt) {
        const int cur = nt & 1;
        const int ntn = (nt + 1) & 31;

#pragma unroll
        for (int rnd = 0; rnd < 2; rnd++) {
            const int row = s_row + rnd * 32;
            const int swr = (s_ch * 8) ^ ((row & 7) << 3);
            const int c = rnd * 256 + t;
            gload_lds16(Kp + base_nd + (size_t)(ntn * 64 + row) * 64 + swr, &KV[cur ^ 1][0][c * 8]);
            gload_lds16(Vt + base_nd + (size_t)row * 2048 + ntn * 64 + swr, &KV[cur ^ 1][1][c * 8]);
        }

        const unsigned short* kbuf = KV[cur][0];
        const unsigned short* vbuf = KV[cur][1];

        bf16x8 kreg[2][4];
#pragma unroll
        for (int kblk = 0; kblk < 2; kblk++)
#pragma unroll
            for (int dstep = 0; dstep < 4; dstep++)
                kreg[kblk][dstep] = *(const bf16x8*)&kbuf[foff[kblk][dstep]];

        floatx16 st[2];
        st[0] = (floatx16)0.0f; st[1] = (floatx16)0.0f;
#pragma unroll
        for (int dstep = 0; dstep < 4; dstep++) {
            st[0] = __builtin_amdgcn_mfma_f32_32x32x16_bf16(kreg[0][dstep], qf[dstep], st[0], 0, 0, 0);
            st[1] = __builtin_amdgcn_mfma_f32_32x32x16_bf16(kreg[1][dstep], qf[dstep], st[1], 0, 0, 0);
        }

#pragma unroll
        for (int kblk = 0; kblk < 2; kblk++)
#pragma unroll
            for (int i = 0; i < 16; i += 4) {
                float p0 = __builtin_amdgcn_exp2f(st[kblk][i + 0]);
                float p1 = __builtin_amdgcn_exp2f(st[kblk][i + 1]);
                float p2 = __builtin_amdgcn_exp2f(st[kblk][i + 2]);
                float p3 = __builtin_amdgcn_exp2f(st[kblk][i + 3]);
                st[kblk][i + 0] = p0; st[kblk][i + 1] = p1;
                st[kblk][i + 2] = p2; st[kblk][i + 3] = p3;
                l4[0] += p0; l4[1] += p1; l4[2] += p2; l4[3] += p3;
            }

        unsigned W[16];
#pragma unroll
        for (int kblk = 0; kblk < 2; kblk++)
#pragma unroll
            for (int q2 = 0; q2 < 4; q2++) {
                const int m = kblk * 4 + q2;
                W[2 * m]     = cvtpk(st[kblk][4 * q2 + 0], st[kblk][4 * q2 + 1]);
                W[2 * m + 1] = cvtpk(st[kblk][4 * q2 + 2], st[kblk][4 * q2 + 3]);
            }

        bf16x8 vreg[2][4];
#pragma unroll
        for (int dblk = 0; dblk < 2; dblk++)
#pragma unroll
            for (int kstep = 0; kstep < 4; kstep++)
                vreg[dblk][kstep] = *(const bf16x8*)&vbuf[foff[dblk][kstep]];

#pragma unroll
        for (int kstep = 0; kstep < 4; kstep++) {
            uint2v r0 = __builtin_amdgcn_permlane32_swap(W[4 * kstep + 0], W[4 * kstep + 2], false, false);
            uint2v r1 = __builtin_amdgcn_permlane32_swap(W[4 * kstep + 1], W[4 * kstep + 3], false, false);
            union { unsigned u[4]; bf16x8 v; } pu;
            pu.u[0] = r0[0]; pu.u[1] = r1[0]; pu.u[2] = r0[1]; pu.u[3] = r1[1];
            o2[0] = __builtin_amdgcn_mfma_f32_32x32x16_bf16(vreg[0][kstep], pu.v, o2[0], 0, 0, 0);
            o2[1] = __builtin_amdgcn_mfma_f32_32x32x16_bf16(vreg[1][kstep], pu.v, o2[1], 0, 0, 0);
        }

        __syncthreads();
    }

    const int bb = head >> 4, h = head & 15;
    const int qg = q0w + l31;
    const float l_own = (l4[0] + l4[1]) + (l4[2] + l4[3]);
    const float inv = 1.0f / (l_own + xswap32(l_own));
    unsigned short* obase = O + ((size_t)(bb * 2048 + qg)) * 1024 + h * 64 + hb * 4;
#pragma unroll
    for (int dblk = 0; dblk < 2; dblk++)
#pragma unroll
        for (int q2 = 0; q2 < 4; q2++) {
            uint2 pr;
            pr.x = cvtpk(o2[dblk][4 * q2 + 0] * inv, o2[dblk][4 * q2 + 1] * inv);
            pr.y = cvtpk(o2[dblk][4 * q2 + 2] * inv, o2[dblk][4 * q2 + 3] * inv);
            *(uint2*)(obase + dblk * 32 + q2 * 8) = pr;
        }
}

// ---------- launch ----------

extern "C" void kernel_launch(void* const* d_in, const int* in_sizes, int n_in,
                              void* d_out, int out_size, void* d_ws, size_t ws_size,
                              hipStream_t stream) {
    const float* x     = (const float*)d_in[0];
    const float* w_qkv = (const float*)d_in[1];
    const float* w_out = (const float*)d_in[2];
    const float* b_out = (const float*)d_in[3];
    float* out = (float*)d_out;

    unsigned short* xb  = (unsigned short*)d_ws;
    unsigned short* wqb = xb  + (size_t)8192 * 1024;
    unsigned short* wob = wqb + (size_t)3072 * 1024;
    unsigned short* q   = wob + (size_t)1024 * 1024;
    unsigned short* k   = q   + (size_t)64 * 2048 * 64;
    unsigned short* vt  = k   + (size_t)64 * 2048 * 64;
    unsigned short* ob  = vt  + (size_t)64 * 2048 * 64;

    f2b_kernel<<<8192, 256, 0, stream>>>(x, xb, 8192 * 1024);
    f2b_kernel<<<3072, 256, 0, stream>>>(w_qkv, wqb, 3072 * 1024);
    f2b_kernel<<<1024, 256, 0, stream>>>(w_out, wob, 1024 * 1024);

    gemm8p<<<384, 512, 0, stream>>>(xb, wqb, q, k, vt);
    attn_kernel<<<1024, 256, 0, stream>>>(q, k, vt, ob);
    gemm_bt<<<512, 256, 0, stream>>>(ob, wob, 8192, 1024, 1024, out, b_out);
}